// Round 1
// baseline (106.002 us; speedup 1.0000x reference)
//
#include <hip/hip_runtime.h>

// A5ExactScan: s_{t+1} = mul[x_t, s_t] over T=2048, per row (B=16384), s0=0.
// Output: one-hot logits (B,60) with 5.0 at final state.
//
// Thread-per-row, Cayley table staged in LDS premultiplied by 4 so the
// per-step dependency chain is exactly: v_add_u32 -> ds_read_b32.

#define T_LEN 2048
#define NTOK 60
#define BROWS 64  // rows per block == block size (1 wave per block)

__global__ __launch_bounds__(BROWS) void a5_scan_kernel(
    const int* __restrict__ ids, const int* __restrict__ mul,
    float* __restrict__ out) {
  // LDS table: tab[x*60+s] = 4*mul[x*60+s]  (next state's byte offset term)
  __shared__ uint32_t tab[NTOK * NTOK];
  const int lane = threadIdx.x;
  for (int i = lane; i < NTOK * NTOK; i += BROWS)
    tab[i] = ((uint32_t)mul[i]) << 2;
  __syncthreads();

  const int row = blockIdx.x * BROWS + lane;
  const int4* rp = (const int4*)(ids + (size_t)row * T_LEN);
  const char* tb = (const char*)tab;

  // Current 16 tokens (64B per lane -> full cache-line utilization).
  int4 c0 = rp[0], c1 = rp[1], c2 = rp[2], c3 = rp[3];

  uint32_t s4 = 0;  // 4 * state; state0 = 0 (identity id)

#define STEP(X)                                      \
  do {                                               \
    uint32_t base_ = (uint32_t)(X)*240u;             \
    s4 = *(const uint32_t*)(tb + base_ + s4);        \
  } while (0)

  for (int t = 0; t < T_LEN; t += 16) {
    int4 n0, n1, n2, n3;
    const bool more = (t + 16) < T_LEN;
    if (more) {
      const int4* np = rp + (t >> 2) + 4;
      n0 = np[0];
      n1 = np[1];
      n2 = np[2];
      n3 = np[3];
    }
    // Consume the 16 buffered tokens; bases are off the dependency chain.
    STEP(c0.x); STEP(c0.y); STEP(c0.z); STEP(c0.w);
    STEP(c1.x); STEP(c1.y); STEP(c1.z); STEP(c1.w);
    STEP(c2.x); STEP(c2.y); STEP(c2.z); STEP(c2.w);
    STEP(c3.x); STEP(c3.y); STEP(c3.z); STEP(c3.w);
    if (more) {
      c0 = n0; c1 = n1; c2 = n2; c3 = n3;
    }
  }
#undef STEP

  const uint32_t s = s4 >> 2;
  // One-hot row write: 15 x float4 = 60 floats, fully overwrites output.
  float4* op = (float4*)(out + (size_t)row * NTOK);
#pragma unroll
  for (int j = 0; j < 15; ++j) {
    float4 v;
    v.x = ((uint32_t)(4 * j + 0) == s) ? 5.0f : 0.0f;
    v.y = ((uint32_t)(4 * j + 1) == s) ? 5.0f : 0.0f;
    v.z = ((uint32_t)(4 * j + 2) == s) ? 5.0f : 0.0f;
    v.w = ((uint32_t)(4 * j + 3) == s) ? 5.0f : 0.0f;
    op[j] = v;
  }
}

extern "C" void kernel_launch(void* const* d_in, const int* in_sizes, int n_in,
                              void* d_out, int out_size, void* d_ws,
                              size_t ws_size, hipStream_t stream) {
  const int* ids = (const int*)d_in[0];
  const int* mul = (const int*)d_in[1];
  float* out = (float*)d_out;

  const int B = in_sizes[0] / T_LEN;  // 16384
  const int grid = B / BROWS;         // 256 blocks x 64 threads = 1 row/thread
  a5_scan_kernel<<<grid, BROWS, 0, stream>>>(ids, mul, out);
}